// Round 6
// baseline (177.139 us; speedup 1.0000x reference)
//
#include <hip/hip_runtime.h>
#include <hip/hip_bf16.h>

#define BB 2
#define CC 2
#define NN 1024
#define F0V 64
#define HH 8
#define FFV 64
#define BCHN (BB*CC*HH)          // 32
#define SVN  (BB*CC*HH*NN)       // 32768

typedef _Float16 f16x8 __attribute__((ext_vector_type(8)));
typedef _Float16 f16x4 __attribute__((ext_vector_type(4)));
typedef __fp16 h16x2 __attribute__((ext_vector_type(2)));   // cvt_pkrtz native type
typedef float f32x4 __attribute__((ext_vector_type(4)));

// ---------------- Packed adjacency bitmask: bmg[b][n][16] u64, bit m = allowed ----------------
__global__ __launch_bounds__(256) void build_mask(const int* __restrict__ adj,
                                                  unsigned long long* __restrict__ bmg)
{
  const int wg = blockIdx.x*4 + (threadIdx.x >> 6);   // 256 blocks x 4 waves = 1024 waves
  const int lane = threadIdx.x & 63;
  for (int idx = wg; idx < BB*NN*16; idx += 1024) {
    const int b = idx >> 14;
    const int n = (idx >> 4) & (NN - 1);
    const int word = idx & 15;
    const int m = word*64 + lane;
    const int pred = (adj[((size_t)b*NN + n)*NN + m] != 0) || (m == n);
    unsigned long long bits = __ballot(pred);
    if (lane == 0) bmg[idx] = bits;
  }
}

// ---------------- Convert x fp32 -> f16 ----------------
__global__ __launch_bounds__(256) void convert_x(const float* __restrict__ x,
                                                 _Float16* __restrict__ xh)
{
  const int i = blockIdx.x*256 + threadIdx.x;
  const float4 v = ((const float4*)x)[i];
  f16x4 o; o[0]=(_Float16)v.x; o[1]=(_Float16)v.y; o[2]=(_Float16)v.z; o[3]=(_Float16)v.w;
  ((f16x4*)xh)[i] = o;
}

// ---------------- Transpose weights: w [ch][K][64] fp32 -> wT [ch][64][K] f16 ----------------
__global__ __launch_bounds__(256) void transpose_w(const float* __restrict__ w,
                                                   _Float16* __restrict__ wT, int K)
{
  __shared__ __align__(16) _Float16 tile[64*72];
  const int ch = blockIdx.y, k0 = blockIdx.x*64;
  const int t = threadIdx.x;
  const float* src = w + ((size_t)ch*K + k0)*64;
  #pragma unroll
  for (int j = 0; j < 4; ++j) {
    const int u = t + j*256;
    const int k = u >> 4, seg = u & 15;
    const float4 v = ((const float4*)src)[(size_t)k*16 + seg];
    tile[(seg*4+0)*72 + k] = (_Float16)v.x;
    tile[(seg*4+1)*72 + k] = (_Float16)v.y;
    tile[(seg*4+2)*72 + k] = (_Float16)v.z;
    tile[(seg*4+3)*72 + k] = (_Float16)v.w;
  }
  __syncthreads();
  _Float16* dst = wT + (size_t)ch*64*K + k0;
  #pragma unroll
  for (int j = 0; j < 2; ++j) {
    const int u = t + j*256;
    const int f = u >> 3, seg = u & 7;
    const f16x8 o = *(const f16x8*)&tile[f*72 + seg*8];
    *(f16x8*)(dst + (size_t)f*K + seg*8) = o;
  }
}

// ---------------- Projection via MFMA: C[32 rows][64 f] = A[rows][K] @ wT[f][K]^T ----------------
template<int K>
__global__ __launch_bounds__(256) void proj_mfma(
    const _Float16* __restrict__ A,      // [bc][N][K]
    const _Float16* __restrict__ wT,     // [c*HH+h][64][K]
    const float* __restrict__ asrc, const float* __restrict__ adst,
    _Float16* __restrict__ HpT, float* __restrict__ s_out, float* __restrict__ d_out)
{
  __shared__ float sp[4][32], sd[4][32];
  const int bch = blockIdx.y;
  const int h = bch % HH; const int bc = bch / HH; const int c = bc % CC;
  const int row0 = blockIdx.x*32;
  const int t = threadIdx.x;
  const int w = t >> 6, lane = t & 63;
  const int colr = lane & 15, quad = lane >> 4;

  const _Float16* Arow0 = A + ((size_t)bc*NN + row0 + colr)*K;
  const _Float16* Arow1 = Arow0 + (size_t)16*K;
  const _Float16* Brow  = wT + ((size_t)(c*HH + h)*64 + w*16 + colr)*K;

  f32x4 acc0 = {0.f,0.f,0.f,0.f}, acc1 = {0.f,0.f,0.f,0.f};
  #pragma unroll 4
  for (int kb = 0; kb < K; kb += 32) {
    const f16x8 a0 = *(const f16x8*)(Arow0 + kb + quad*8);
    const f16x8 a1 = *(const f16x8*)(Arow1 + kb + quad*8);
    const f16x8 bf = *(const f16x8*)(Brow  + kb + quad*8);
    acc0 = __builtin_amdgcn_mfma_f32_16x16x32_f16(a0, bf, acc0, 0, 0, 0);
    acc1 = __builtin_amdgcn_mfma_f32_16x16x32_f16(a1, bf, acc1, 0, 0, 0);
  }

  const float af = asrc[(c*HH + h)*64 + w*16 + colr];
  const float bf_ = adst[(c*HH + h)*64 + w*16 + colr];
  _Float16* HT = HpT + ((size_t)bch*64 + w*16 + colr)*NN + row0;

  #pragma unroll
  for (int mt = 0; mt < 2; ++mt) {
    const f32x4 a = mt ? acc1 : acc0;
    f16x4 hv;
    #pragma unroll
    for (int i = 0; i < 4; ++i) {
      const float v = a[i];
      hv[i] = (_Float16)v;
      const float ex = __expf(2.f*v);
      const float th = 1.f - 2.f/(ex + 1.f);         // tanh(v)
      float ps = th * af, pd = th * bf_;
      #pragma unroll
      for (int off = 1; off < 16; off <<= 1) {
        ps += __shfl_xor(ps, off);
        pd += __shfl_xor(pd, off);
      }
      if (colr == 0) {
        sp[w][mt*16 + quad*4 + i] = ps;
        sd[w][mt*16 + quad*4 + i] = pd;
      }
    }
    *(f16x4*)(HT + mt*16 + quad*4) = hv;
  }
  __syncthreads();
  if (t < 32) {
    const float sv = sp[0][t] + sp[1][t] + sp[2][t] + sp[3][t];
    const float dv = sd[0][t] + sd[1][t] + sd[2][t] + sd[3][t];
    s_out[bch*NN + row0 + t] = sv;
    d_out[bch*NN + row0 + t] = dv;
  }
}

// ---------------- Fused attention v2: register P (A-frags), global B-frags, K-split waves ----------
// grid (N/32, 32 bch), 256 thr. Wave w owns K-quarter [w*256, w*256+256).
// Per wave: 2 row-tiles x 4 f-tiles accumulators; cross-wave reduce via LDS at the end.
template<int LAYER>
__global__ __launch_bounds__(256) void attn_mfma(
    const _Float16* __restrict__ HpT, const float* __restrict__ s_arr,
    const float* __restrict__ d_arr, const unsigned long long* __restrict__ bmg,
    _Float16* __restrict__ outp)
{
  __shared__ float partials[4*32*64];   // 32 KB: [w][r][f]
  __shared__ __align__(16) float d_lds[NN];  // 4 KB
  __shared__ float dsP[4][32];
  __shared__ float red4[4];
  const int bch = blockIdx.y;
  const int b = bch / (CC*HH);
  const int row0 = blockIdx.x*32;
  const int t = threadIdx.x;
  const int w = t >> 6, lane = t & 63;
  const int colr = lane & 15, quad = lane >> 4;

  // stage d, compute maxd (global softmax shift)
  float4 dv4 = ((const float4*)(d_arr + (size_t)bch*NN))[t];
  ((float4*)d_lds)[t] = dv4;
  float mxl = fmaxf(fmaxf(dv4.x, dv4.y), fmaxf(dv4.z, dv4.w));
  #pragma unroll
  for (int off = 1; off < 64; off <<= 1) mxl = fmaxf(mxl, __shfl_xor(mxl, off));
  if (lane == 0) red4[w] = mxl;
  __syncthreads();
  const float maxd = fmaxf(fmaxf(red4[0], red4[1]), fmaxf(red4[2], red4[3]));

  // per-lane rows: r0 = colr, r1 = colr+16
  const float s0 = s_arr[(size_t)bch*NN + row0 + colr];
  const float s1 = s_arr[(size_t)bch*NN + row0 + 16 + colr];
  const float so0 = s0 + maxd, so1 = s1 + maxd;
  const float offs0 = fmaxf(so0, 0.2f*so0);   // >= lrelu(s0+d) for all d
  const float offs1 = fmaxf(so1, 0.2f*so1);
  const unsigned long long* bm0 = bmg + ((size_t)b*NN + row0 + colr)*16;
  const unsigned long long* bm1 = bmg + ((size_t)b*NN + row0 + 16 + colr)*16;

  const _Float16* Bg = HpT + (size_t)bch*64*NN;
  f32x4 acc[2][4];
  #pragma unroll
  for (int rt = 0; rt < 2; ++rt)
    #pragma unroll
    for (int ft = 0; ft < 4; ++ft) acc[rt][ft] = (f32x4){0.f,0.f,0.f,0.f};
  float ds0 = 0.f, ds1 = 0.f;

  for (int kw = 0; kw < 4; ++kw) {                 // 64-k words within this wave's quarter
    const unsigned long long wd0 = bm0[w*4 + kw];
    const unsigned long long wd1 = bm1[w*4 + kw];
    #pragma unroll
    for (int ks2 = 0; ks2 < 2; ++ks2) {            // two 32-k MFMA steps per word
      const int kb = w*256 + kw*64 + ks2*32;
      const unsigned mb0 = (unsigned)((wd0 >> (ks2*32 + quad*8)) & 0xFFull);
      const unsigned mb1 = (unsigned)((wd1 >> (ks2*32 + quad*8)) & 0xFFull);
      const float4 dqa = *(const float4*)&d_lds[kb + quad*8];
      const float4 dqb = *(const float4*)&d_lds[kb + quad*8 + 4];
      const float dd[8] = {dqa.x,dqa.y,dqa.z,dqa.w, dqb.x,dqb.y,dqb.z,dqb.w};
      union { f16x8 v; h16x2 h[4]; } A0, A1;
      #pragma unroll
      for (int jp = 0; jp < 4; ++jp) {
        float pv[4];
        #pragma unroll
        for (int jj = 0; jj < 2; ++jj) {
          const int j = jp*2 + jj;
          const float dj = dd[j];
          const float e0 = s0 + dj;
          const float l0 = fmaxf(e0, 0.2f*e0);
          const float q0 = ((mb0 >> j) & 1u) ? __expf(l0 - offs0) : 0.f;
          const float e1 = s1 + dj;
          const float l1 = fmaxf(e1, 0.2f*e1);
          const float q1 = ((mb1 >> j) & 1u) ? __expf(l1 - offs1) : 0.f;
          ds0 += q0; ds1 += q1;
          pv[jj] = q0; pv[2+jj] = q1;
        }
        A0.h[jp] = __builtin_amdgcn_cvt_pkrtz(pv[0], pv[1]);
        A1.h[jp] = __builtin_amdgcn_cvt_pkrtz(pv[2], pv[3]);
      }
      // B-frags straight from global: lane supplies HpT[ft*16+colr][kb+quad*8 .. +7]
      #pragma unroll
      for (int ft = 0; ft < 4; ++ft) {
        const f16x8 bf = *(const f16x8*)(Bg + (size_t)(ft*16 + colr)*NN + kb + quad*8);
        acc[0][ft] = __builtin_amdgcn_mfma_f32_16x16x32_f16(A0.v, bf, acc[0][ft], 0, 0, 0);
        acc[1][ft] = __builtin_amdgcn_mfma_f32_16x16x32_f16(A1.v, bf, acc[1][ft], 0, 0, 0);
      }
    }
  }

  // denominator partials: sum over quads (lanes colr, colr+16, colr+32, colr+48)
  ds0 += __shfl_xor(ds0, 16); ds0 += __shfl_xor(ds0, 32);
  ds1 += __shfl_xor(ds1, 16); ds1 += __shfl_xor(ds1, 32);
  if (quad == 0) { dsP[w][colr] = ds0; dsP[w][16 + colr] = ds1; }

  // write C partials: C/D layout col=colr, row=quad*4+i
  float* pw = partials + w*(32*64);
  #pragma unroll
  for (int rt = 0; rt < 2; ++rt)
    #pragma unroll
    for (int ft = 0; ft < 4; ++ft)
      #pragma unroll
      for (int i = 0; i < 4; ++i)
        pw[(rt*16 + quad*4 + i)*64 + ft*16 + colr] = acc[rt][ft][i];
  __syncthreads();

  // final: thread t -> row r = t>>3, features f0 = (t&7)*8 .. +7
  const int r = t >> 3, f0 = (t & 7)*8;
  const float dsum = dsP[0][r] + dsP[1][r] + dsP[2][r] + dsP[3][r];
  const float inv = 1.f / dsum;
  float4 c0 = {0.f,0.f,0.f,0.f}, c1 = {0.f,0.f,0.f,0.f};
  #pragma unroll
  for (int w4 = 0; w4 < 4; ++w4) {
    const float4 a0 = *(const float4*)&partials[(w4*32 + r)*64 + f0];
    const float4 a1 = *(const float4*)&partials[(w4*32 + r)*64 + f0 + 4];
    c0.x += a0.x; c0.y += a0.y; c0.z += a0.z; c0.w += a0.w;
    c1.x += a1.x; c1.y += a1.y; c1.z += a1.z; c1.w += a1.w;
  }
  const float cv[8] = {c0.x,c0.y,c0.z,c0.w, c1.x,c1.y,c1.z,c1.w};
  f16x8 o;
  #pragma unroll
  for (int i = 0; i < 8; ++i) {
    float v = cv[i] * inv;
    if (LAYER == 1) v = v > 0.f ? v : expm1f(v);
    o[i] = (_Float16)v;
  }
  const int bc = bch / HH, h = bch % HH;
  if (LAYER == 1)
    *(f16x8*)(outp + ((size_t)bc*NN + row0 + r)*512 + h*64 + f0) = o;
  else
    *(f16x8*)(outp + ((size_t)bch*NN + row0 + r)*64 + f0) = o;
}

// ---------------- Mean over heads (f16 in) -> fp32 out ----------------
__global__ __launch_bounds__(256) void reduce_heads(
    const _Float16* __restrict__ out2, float* __restrict__ out)
{
  const int o = blockIdx.x*256 + threadIdx.x;
  const int f = o & 63;
  const int n = (o >> 6) & (NN - 1);
  const int bc = o >> 16;
  float acc = 0.f;
  #pragma unroll
  for (int h = 0; h < HH; ++h)
    acc += (float)out2[(((size_t)bc*HH + h)*NN + n)*FFV + f];
  out[o] = acc * 0.125f;
}

extern "C" void kernel_launch(void* const* d_in, const int* in_sizes, int n_in,
                              void* d_out, int out_size, void* d_ws, size_t ws_size,
                              hipStream_t stream)
{
  const float* x   = (const float*)d_in[0];
  const int*   adj = (const int*)d_in[1];
  const float* w1  = (const float*)d_in[2];
  const float* as1 = (const float*)d_in[3];
  const float* ad1 = (const float*)d_in[4];
  const float* w2  = (const float*)d_in[5];
  const float* as2 = (const float*)d_in[6];
  const float* ad2 = (const float*)d_in[7];

  char* w8 = (char*)d_ws;
  _Float16* HpT = (_Float16*)(w8);                         // 4 MB  [bch][64][N]
  _Float16* XB  = (_Float16*)(w8 + (4u<<20));              // 4 MB  x1 [bc][N][512] then out2 [bch][N][64]
  _Float16* xh  = (_Float16*)(w8 + (8u<<20));              // 512 KB [bc][N][64]
  _Float16* w1T = (_Float16*)(w8 + (8u<<20) + (512u<<10)); // 128 KB [ch][64][64]
  _Float16* w2T = (_Float16*)(w8 + (8u<<20) + (768u<<10)); // 1 MB   [ch][64][512]
  float* s_v = (float*)(w8 + (10u<<20));                   // 128 KB
  float* d_v = (float*)(w8 + (10u<<20) + SVN*4);           // 128 KB
  unsigned long long* bmg = (unsigned long long*)(w8 + (10u<<20) + SVN*8);  // 256 KB

  convert_x<<<256, 256, 0, stream>>>(x, xh);
  transpose_w<<<dim3(1, CC*HH), 256, 0, stream>>>(w1, w1T, 64);
  transpose_w<<<dim3(8, CC*HH), 256, 0, stream>>>(w2, w2T, 512);
  build_mask<<<256, 256, 0, stream>>>(adj, bmg);
  proj_mfma<64><<<dim3(NN/32, BCHN), 256, 0, stream>>>(xh, w1T, as1, ad1, HpT, s_v, d_v);
  attn_mfma<1><<<dim3(NN/32, BCHN), 256, 0, stream>>>(HpT, s_v, d_v, bmg, XB);
  proj_mfma<512><<<dim3(NN/32, BCHN), 256, 0, stream>>>(XB, w2T, as2, ad2, HpT, s_v, d_v);
  attn_mfma<2><<<dim3(NN/32, BCHN), 256, 0, stream>>>(HpT, s_v, d_v, bmg, XB);
  reduce_heads<<<dim3((unsigned)(out_size/256)), 256, 0, stream>>>(XB, (float*)d_out);
}